// Round 6
// baseline (83.268 us; speedup 1.0000x reference)
//
#include <hip/hip_runtime.h>
#include <math.h>

// Problem constants
#define B_N   2048
#define D_IN_ 16
#define Q_N   512
#define H_N   128

#define QCHUNK 32                      // q's per block
#define NQC    (Q_N / QCHUNK)          // 16
#define QPC    (QCHUNK / 4)            // 8 quads per chunk
#define NQP    (QPC / 2)               // 4 quad-pairs
#define NB     8                       // rows per thread
#define RPB    16                      // rows per block
#define NRB    (B_N / RPB)             // 128

typedef float v2f __attribute__((ext_vector_type(2)));

static constexpr float kC = 2.88539008177792681472f;  // 2 * log2(e)

// ---------------------------------------------------------------------------
// Single fused kernel (round-5 verified math; packed inner loop via
// __builtin_elementwise_fma on v2f — the builtin path round 2 proved exact).
//   out[b] = sum_chunks [ Sc*(sumW2+b2) + sum_h W2[h] * sum_quads N(F)/P(F) ]
// Per quad (4 q's): sum_i -2 y_i/(1+E_i F) = N(F)/P(F); N deg3 (y folded),
// P deg4 (p0=1); E = exp2(kC*u_qh), F = exp2(kC*v_bh), kC = 2*log2(e).
// Coef tile layout [qp][coef][h][2]: the two quads of a pair sit adjacent ->
// one aligned ds_read_b64 per v2f coefficient (contiguous across lanes).
// Inner: 8 pk_fma + 2 rcp per (quadpair,row) = 8 elements.
// grid = 128 row-blocks x 16 q-chunks, block = 256 (128 h x 2 row-groups).
// ---------------------------------------------------------------------------
__global__ __launch_bounds__(256, 4) void fused_kernel(
    const float* __restrict__ input,
    const float* __restrict__ eq,
    const float* __restrict__ qx,
    const float* __restrict__ W1,
    const float* __restrict__ b1,
    const float* __restrict__ W2,
    const float* __restrict__ b2,
    float* __restrict__ out)
{
    __shared__ __align__(16) float c_s[NQP * 8 * H_N * 2];  // 32 KB
    __shared__ float in_s[RPB * D_IN_];      // 256 floats
    __shared__ float qx_s[QCHUNK * 2];       // 64 floats
    __shared__ float y_s[QCHUNK];            // -2*sin(qx.eq)
    __shared__ float part[4][NB];
    __shared__ float Sc_s, w2sum_s;

    const int t    = threadIdx.x;
    const int rb   = blockIdx.x & (NRB - 1); // row-block [0,128)
    const int qc   = blockIdx.x >> 7;        // q-chunk   [0,16)
    const int h    = t & 127;
    const int bg   = t >> 7;                 // row group 0/1
    const int lane = t & 63;
    const int w    = t >> 6;

    // ---- phase 0: stage input rows + qx chunk; y + Sc (wave 0); sum W2 ----
    in_s[t] = input[rb * (RPB * D_IN_) + t];
    if (t < QCHUNK * 2) qx_s[t] = qx[qc * (QCHUNK * 2) + t];
    if (w == 0) {
        float s = 0.0f;
        if (lane < QCHUNK) {
            const int q = qc * QCHUNK + lane;
            const float a  = fmaf(qx[2 * q + 1], eq[1], qx[2 * q] * eq[0]);
            const float yv = sinf(a);
            y_s[lane] = -2.0f * yv;
            s = yv;
        }
        #pragma unroll
        for (int off = 32; off >= 1; off >>= 1)
            s += __shfl_down(s, off, 64);
        if (lane == 0) Sc_s = s;
    }
    if (w == 1) {                            // sum W2 over 128 h
        float s = W2[lane] + W2[64 + lane];
        #pragma unroll
        for (int off = 32; off >= 1; off >>= 1)
            s += __shfl_down(s, off, 64);
        if (lane == 0) w2sum_s = s;
    }
    const float w2 = W2[h];
    __syncthreads();

    // ---- phase 1: coef tile. thread (h,bg) builds quads bg*4+{0..3} ----
    {
        const float w1a = W1[h], w1b = W1[H_N + h], bh = b1[h];
        #pragma unroll
        for (int k = 0; k < 4; ++k) {
            const int qd = bg * 4 + k;       // quad index [0,8)
            float n0 = 0, n1 = 0, n2 = 0, n3 = 0;
            float p1 = 0, p2 = 0, p3 = 0, p4 = 0;
            #pragma unroll
            for (int i = 0; i < 4; ++i) {
                const int ql = qd * 4 + i;   // local q [0,32)
                const float x0 = qx_s[2 * ql], x1 = qx_s[2 * ql + 1];
                const float u = fmaf(x1, w1b, fmaf(x0, w1a, bh));
                const float E = __builtin_amdgcn_exp2f(u * kC);
                const float y = y_s[ql];     // already -2*sin
                // N' = N*(1+Ex) + y*P ; P' = P*(1+Ex)  (descending order)
                n3 = fmaf(E, n2, fmaf(y, p3, n3));
                n2 = fmaf(E, n1, fmaf(y, p2, n2));
                n1 = fmaf(E, n0, fmaf(y, p1, n1));
                n0 = n0 + y;                 // p0 == 1
                p4 = fmaf(E, p3, p4);
                p3 = fmaf(E, p2, p3);
                p2 = fmaf(E, p1, p2);
                p1 = p1 + E;
            }
            // [qp][coef][h][2] : pair-interleaved for b64 phase-3 reads
            float* dst = c_s + (qd >> 1) * (8 * H_N * 2) + (h << 1) + (qd & 1);
            dst[0 * 256] = n0; dst[1 * 256] = n1;
            dst[2 * 256] = n2; dst[3 * 256] = n3;
            dst[4 * 256] = p1; dst[5 * 256] = p2;
            dst[6 * 256] = p3; dst[7 * 256] = p4;
        }
    }

    // ---- phase 2: F for my 8 rows (in_s is pre-barrier data) ----
    v2f F2[NB], acc2[NB];
    {
        float w1c[D_IN_];
        #pragma unroll
        for (int d = 0; d < D_IN_; ++d)
            w1c[d] = W1[(2 + d) * H_N + h];
        const float4* in4 = (const float4*)in_s;
        #pragma unroll
        for (int r = 0; r < NB; ++r) {
            const int row = bg * NB + r;
            float s = 0.0f;
            #pragma unroll
            for (int k = 0; k < 4; ++k) {
                const float4 a = in4[row * 4 + k];
                s = fmaf(a.x, w1c[4 * k + 0], s);
                s = fmaf(a.y, w1c[4 * k + 1], s);
                s = fmaf(a.z, w1c[4 * k + 2], s);
                s = fmaf(a.w, w1c[4 * k + 3], s);
            }
            const float f = __builtin_amdgcn_exp2f(s * kC);
            F2[r].x = f; F2[r].y = f;
            acc2[r].x = 0.0f; acc2[r].y = 0.0f;
        }
    }
    __syncthreads();

    // ---- phase 3: packed rational inner (8 pk_fma + 2 rcp per 8 elems) ----
    const v2f one2 = {1.0f, 1.0f};
    #pragma unroll
    for (int qp = 0; qp < NQP; ++qp) {
        const float* cp = c_s + qp * (8 * H_N * 2) + (h << 1);
        const v2f n0 = *(const v2f*)(cp + 0 * 256);
        const v2f n1 = *(const v2f*)(cp + 1 * 256);
        const v2f n2 = *(const v2f*)(cp + 2 * 256);
        const v2f n3 = *(const v2f*)(cp + 3 * 256);
        const v2f c1 = *(const v2f*)(cp + 4 * 256);
        const v2f c2 = *(const v2f*)(cp + 5 * 256);
        const v2f c3 = *(const v2f*)(cp + 6 * 256);
        const v2f c4 = *(const v2f*)(cp + 7 * 256);
        #pragma unroll
        for (int r = 0; r < NB; ++r) {
            const v2f Fr = F2[r];
            v2f den = __builtin_elementwise_fma(c4, Fr, c3);
            den = __builtin_elementwise_fma(den, Fr, c2);
            den = __builtin_elementwise_fma(den, Fr, c1);
            den = __builtin_elementwise_fma(den, Fr, one2);
            v2f num = __builtin_elementwise_fma(n3, Fr, n2);
            num = __builtin_elementwise_fma(num, Fr, n1);
            num = __builtin_elementwise_fma(num, Fr, n0);
            v2f rc;
            rc.x = __builtin_amdgcn_rcpf(den.x);
            rc.y = __builtin_amdgcn_rcpf(den.y);
            acc2[r] = __builtin_elementwise_fma(num, rc, acc2[r]);
        }
    }

    // ---- epilogue: x W2[h], reduce over h, add per-chunk constant ----
    #pragma unroll
    for (int r = 0; r < NB; ++r) {
        float p = (acc2[r].x + acc2[r].y) * w2;
        #pragma unroll
        for (int off = 32; off >= 1; off >>= 1)
            p += __shfl_down(p, off, 64);
        if (lane == 0) part[w][r] = p;
    }
    __syncthreads();

    if (t < 16) {
        const int r = t & 7, g = t >> 3;
        const float k0c = Sc_s * (w2sum_s + b2[0]);   // this chunk's constant
        const float s = part[2 * g][r] + part[2 * g + 1][r] + k0c;
        atomicAdd(out + rb * RPB + g * NB + r, s);
    }
}

// ---------------------------------------------------------------------------
extern "C" void kernel_launch(void* const* d_in, const int* in_sizes, int n_in,
                              void* d_out, int out_size, void* d_ws, size_t ws_size,
                              hipStream_t stream)
{
    (void)in_sizes; (void)n_in; (void)d_ws; (void)ws_size;
    const float* input = (const float*)d_in[0];
    const float* eq    = (const float*)d_in[1];
    const float* qx    = (const float*)d_in[2];
    const float* W1    = (const float*)d_in[3];
    const float* b1    = (const float*)d_in[4];
    const float* W2    = (const float*)d_in[5];
    const float* b2    = (const float*)d_in[6];
    float* out = (float*)d_out;

    hipMemsetAsync(d_out, 0, (size_t)out_size * sizeof(float), stream);
    fused_kernel<<<dim3(NRB * NQC), dim3(256), 0, stream>>>(
        input, eq, qx, W1, b1, W2, b2, out);
}